// Round 22
// baseline (214.171 us; speedup 1.0000x reference)
//
#include <hip/hip_runtime.h>

#define IN_CH  64
#define OUT_CH 32
#define BLOCK  8

using short8 = __attribute__((ext_vector_type(8))) short;
using f32x4v = __attribute__((ext_vector_type(4))) float;

// ws layout: argmax M*4 | claimed M | count 256B | list M*4
// R22: overlap srest with compute of j=7-claimed rows (argmax FINAL for
// claimed rows after s7 -- srest only touches unclaimed rows; disjoint).
// Unclaimed rows compacted into a list, finished by small k_computeB.

__global__ void k_prep(int4* __restrict__ argmax4, int n4,
                       int4* __restrict__ claimed4, int nc4, int* __restrict__ count) {
    int i = blockIdx.x * 256 + threadIdx.x;
    if (i == 0) *count = 0;
    if (i < n4) argmax4[i] = make_int4(-1, -1, -1, -1);
    if (i < nc4) claimed4[i] = make_int4(0, 0, 0, 0);
}

// claimed[m]=1 for EVERY valid j=7 mapping. argmax monotone non-decreasing:
// stale filter read = valid lower bound; filtered atomicMax always correct.
__global__ void k_scatter7(const int* __restrict__ pair, int* __restrict__ argmax,
                           unsigned char* __restrict__ claimed, int N) {
    int i = blockIdx.x * 256 + threadIdx.x;
    if (i >= N) return;
    int n = N - 1 - i;                 // descending: high-t first
    int t = 7 * N + n;
    int m = pair[t];
    if (m >= 0) {
        claimed[m] = 1;
        if (argmax[m] < t) atomicMax(&argmax[m], t);
    }
}

__device__ __forceinline__ unsigned cvt_pk_bf16(float lo, float hi) {
    unsigned r;
    asm("v_cvt_pk_bf16_f32 %0, %1, %2" : "=v"(r) : "v"(lo), "v"(hi));
    return r;
}

__device__ __forceinline__ short8 pack8(float4 a, float4 b) {
    union { unsigned u[4]; short8 s; } p;
    p.u[0] = cvt_pk_bf16(a.x, a.y);
    p.u[1] = cvt_pk_bf16(a.z, a.w);
    p.u[2] = cvt_pk_bf16(b.x, b.y);
    p.u[3] = cvt_pk_bf16(b.z, b.w);
    return p.s;
}

// One dispatch, two roles:
//  blocks [0, nA):    computeA -- j=7-claimed rows, NO j-loop (all rows j=7),
//                     garbage rows (unclaimed) store-masked; also compacts
//                     unclaimed row ids into list (1 atomicAdd per subtile).
//  blocks [nA, ...):  scatter_rest -- j=6..0 filtered atomicMax (unclaimed only).
// Correct concurrently: disjoint argmax row sets; computeA's reads of in-flux
// unclaimed rows decode to clamped garbage and never get stored.
__global__ __launch_bounds__(256, 3) void k_mix(
        const float* __restrict__ x, const float* __restrict__ w,
        const int* __restrict__ pair, int* __restrict__ argmax,
        const unsigned char* __restrict__ claimed, float* __restrict__ out,
        int* __restrict__ list, int* __restrict__ count,
        int M, int N, int nA) {
    if ((int)blockIdx.x >= nA) {
        // ---- scatter_rest role
        int n = (blockIdx.x - nA) * 256 + threadIdx.x;
        if (n >= N) return;
        for (int j = 6; j >= 0; --j) {
            int t = j * N + n;
            int m = pair[t];
            if (m >= 0 && !claimed[m] && argmax[m] < t)
                atomicMax(&argmax[m], t);
        }
        return;
    }
    // ---- computeA role: 64 consecutive rows per wave, j=7 only
    const int lane = threadIdx.x & 63;
    const int r16  = lane & 15;
    const int kc   = lane >> 4;
    const int wv   = threadIdx.x >> 6;

    int base = (blockIdx.x * 4 + wv) * 64;
    if (base >= M) return;                 // M % 64 == 0

    const int TH = 7 * N;
    int t_[4], n_[4];
    bool cl[4];
#pragma unroll
    for (int st = 0; st < 4; ++st)
        t_[st] = argmax[base + st * 16 + r16];
#pragma unroll
    for (int st = 0; st < 4; ++st) {
        cl[st] = (t_[st] >= TH);           // claimed row: final, j=7
        n_[st] = cl[st] ? t_[st] - TH : 0; // unclaimed -> dummy row 0
    }

    // compact unclaimed rows (kc==0 lanes only; one atomic per subtile)
#pragma unroll
    for (int st = 0; st < 4; ++st) {
        unsigned long long ub = __ballot(!cl[st] && kc == 0);
        if (ub) {
            int leader = (int)__ffsll(ub) - 1;
            int bp = 0;
            if (lane == leader) bp = atomicAdd(count, __popcll(ub));
            bp = __shfl(bp, leader);
            if (!cl[st] && kc == 0) {
                int pre = (int)__popcll(ub & ((1ull << lane) - 1ull));
                list[bp + pre] = base + st * 16 + r16;
            }
        }
    }

    // B = W[:, j=7] resident (16 VGPRs)
    short8 bf7[2][2];
#pragma unroll
    for (int ot = 0; ot < 2; ++ot)
#pragma unroll
        for (int kk = 0; kk < 2; ++kk) {
            const float* wp = w + ((ot * 16 + r16) * BLOCK + 7) * IN_CH + kk * 32 + kc * 8;
            bf7[ot][kk] = pack8(*(const float4*)wp, *(const float4*)(wp + 4));
        }

    float4 xs[2][4];
    {
        const float* xp = x + (size_t)n_[0] * IN_CH + kc * 8;
        xs[0][0] = *(const float4*)xp;        xs[0][1] = *(const float4*)(xp + 4);
        xs[0][2] = *(const float4*)(xp + 32); xs[0][3] = *(const float4*)(xp + 36);
    }

#pragma unroll
    for (int st = 0; st < 4; ++st) {
        const int cur = st & 1;
        if (st < 3) {
            const float* xp = x + (size_t)n_[st + 1] * IN_CH + kc * 8;
            xs[cur ^ 1][0] = *(const float4*)xp;        xs[cur ^ 1][1] = *(const float4*)(xp + 4);
            xs[cur ^ 1][2] = *(const float4*)(xp + 32); xs[cur ^ 1][3] = *(const float4*)(xp + 36);
        }
        short8 a0 = pack8(xs[cur][0], xs[cur][1]);
        short8 a1 = pack8(xs[cur][2], xs[cur][3]);

        f32x4v acc0 = {0.f, 0.f, 0.f, 0.f};
        f32x4v acc1 = {0.f, 0.f, 0.f, 0.f};
        acc0 = __builtin_amdgcn_mfma_f32_16x16x32_bf16(a0, bf7[0][0], acc0, 0, 0, 0);
        acc0 = __builtin_amdgcn_mfma_f32_16x16x32_bf16(a1, bf7[0][1], acc0, 0, 0, 0);
        acc1 = __builtin_amdgcn_mfma_f32_16x16x32_bf16(a0, bf7[1][0], acc1, 0, 0, 0);
        acc1 = __builtin_amdgcn_mfma_f32_16x16x32_bf16(a1, bf7[1][1], acc1, 0, 0, 0);

        unsigned long long cb = __ballot(cl[st]);    // row r claim = bit r
#pragma unroll
        for (int q = 0; q < 4; ++q) {
            int r = kc * 4 + q;
            if ((cb >> r) & 1ull) {
                size_t ro = (size_t)(base + st * 16 + r) * OUT_CH;
                out[ro + r16]      = acc0[q];
                out[ro + 16 + r16] = acc1[q];
            }
        }
    }
}

// finish the ~13.5% unclaimed rows from the compacted list (j<=6 or unmapped)
__global__ __launch_bounds__(256, 4) void k_computeB(
        const float* __restrict__ x, const float* __restrict__ w,
        const int* __restrict__ argmax, const int* __restrict__ list,
        const int* __restrict__ count, float* __restrict__ out, int M, int N) {
    const int lane = threadIdx.x & 63;
    const int r16  = lane & 15;
    const int kc   = lane >> 4;
    const int wv   = threadIdx.x >> 6;

    int cnt  = *count;
    int nsub = (cnt + 15) >> 4;
    int gw   = blockIdx.x * 4 + wv;
    int nw   = gridDim.x * 4;
    const int N1 = N, N2 = 2 * N, N4 = 4 * N;

    for (int s = gw; s < nsub; s += nw) {
        int  li  = s * 16 + r16;
        bool ok  = li < cnt;
        int  idx = ok ? list[li] : 0;
        int  t   = ok ? argmax[idx] : -1;
        int v = t, j = 0;
        if (v >= N4) { j = 4;  v -= N4; }
        if (v >= N2) { j += 2; v -= N2; }
        if (v >= N1) { j += 1; v -= N1; }
        int jr = (t >= 0) ? j : 8;
        int n  = (t >= 0) ? v : 0;

        const float* xp = x + (size_t)n * IN_CH + kc * 8;
        float4 x0 = *(const float4*)xp;
        float4 x1 = *(const float4*)(xp + 4);
        float4 x2 = *(const float4*)(xp + 32);
        float4 x3 = *(const float4*)(xp + 36);
        short8 a0 = pack8(x0, x1);
        short8 a1 = pack8(x2, x3);
        const short8 zz = (short8)0;

        f32x4v acc0 = {0.f, 0.f, 0.f, 0.f};
        f32x4v acc1 = {0.f, 0.f, 0.f, 0.f};
#pragma unroll
        for (int j2 = 0; j2 < 7; ++j2) {             // j=7 never here
            bool pj = (jr == j2);
            if (__ballot(pj) == 0ull) continue;
            short8 m0 = pj ? a0 : zz;
            short8 m1 = pj ? a1 : zz;
            const float* wp0 = w + ((r16)      * BLOCK + j2) * IN_CH + kc * 8;
            const float* wp1 = w + ((16 + r16) * BLOCK + j2) * IN_CH + kc * 8;
            short8 b00 = pack8(*(const float4*)wp0,        *(const float4*)(wp0 + 4));
            short8 b01 = pack8(*(const float4*)(wp0 + 32), *(const float4*)(wp0 + 36));
            short8 b10 = pack8(*(const float4*)wp1,        *(const float4*)(wp1 + 4));
            short8 b11 = pack8(*(const float4*)(wp1 + 32), *(const float4*)(wp1 + 36));
            acc0 = __builtin_amdgcn_mfma_f32_16x16x32_bf16(m0, b00, acc0, 0, 0, 0);
            acc0 = __builtin_amdgcn_mfma_f32_16x16x32_bf16(m1, b01, acc0, 0, 0, 0);
            acc1 = __builtin_amdgcn_mfma_f32_16x16x32_bf16(m0, b10, acc1, 0, 0, 0);
            acc1 = __builtin_amdgcn_mfma_f32_16x16x32_bf16(m1, b11, acc1, 0, 0, 0);
        }

        unsigned long long okb = __ballot(ok);
#pragma unroll
        for (int q = 0; q < 4; ++q) {
            int r = kc * 4 + q;
            if ((okb >> r) & 1ull) {
                int idxr = __shfl(idx, r);           // row r's out index
                size_t ro = (size_t)idxr * OUT_CH;
                out[ro + r16]      = acc0[q];
                out[ro + 16 + r16] = acc1[q];
            }
        }
    }
}

extern "C" void kernel_launch(void* const* d_in, const int* in_sizes, int n_in,
                              void* d_out, int out_size, void* d_ws, size_t ws_size,
                              hipStream_t stream) {
    const float* x    = (const float*)d_in[0];
    const float* w    = (const float*)d_in[1];
    const int*   pair = (const int*)d_in[2];
    int N = in_sizes[0] / IN_CH;     // 400000
    int M = out_size / OUT_CH;       // 200000

    char*          ws      = (char*)d_ws;
    int*           argmax  = (int*)ws;
    unsigned char* claimed = (unsigned char*)(ws + (size_t)M * 4);
    int*           count   = (int*)(ws + (size_t)M * 5);
    int*           list    = (int*)(ws + (size_t)M * 5 + 256);

    int n4  = M / 4;
    int nc4 = M / 16;
    k_prep<<<(n4 + 255) / 256, 256, 0, stream>>>((int4*)argmax, n4, (int4*)claimed, nc4, count);

    int gN = (N + 255) / 256;        // 1563
    k_scatter7<<<gN, 256, 0, stream>>>(pair, argmax, claimed, N);

    int nA = (M / 64 + 3) / 4;       // 782 computeA blocks
    k_mix<<<nA + gN, 256, 0, stream>>>(x, w, pair, argmax, claimed,
                                       (float*)d_out, list, count, M, N, nA);

    k_computeB<<<512, 256, 0, stream>>>(x, w, argmax, list, count,
                                        (float*)d_out, M, N);
}

// Round 23
// 93.814 us; speedup vs baseline: 2.2829x; 2.2829x over previous
//
#include <hip/hip_runtime.h>

#define IN_CH  64
#define OUT_CH 32
#define BLOCK  8

using short8 = __attribute__((ext_vector_type(8))) short;
using f32x4v = __attribute__((ext_vector_type(4))) float;

// ws layout: argmax M*4 | claimed M bytes.
// R23: R22 overlap retried without the regalloc pathology. No list/count;
// computeB rescans argmax (coalesced, L2-hot). srest role first in grid,
// computeA role is R18's compute verbatim + claim-masked stores.

__global__ void k_prep(int4* __restrict__ argmax4, int n4, int4* __restrict__ claimed4, int nc4) {
    int i = blockIdx.x * 256 + threadIdx.x;
    if (i < n4) argmax4[i] = make_int4(-1, -1, -1, -1);
    if (i < nc4) claimed4[i] = make_int4(0, 0, 0, 0);
}

// claimed[m]=1 for EVERY valid j=7 mapping. argmax monotone non-decreasing:
// stale filter read = valid lower bound; filtered atomicMax always correct.
__global__ void k_scatter7(const int* __restrict__ pair, int* __restrict__ argmax,
                           unsigned char* __restrict__ claimed, int N) {
    int i = blockIdx.x * 256 + threadIdx.x;
    if (i >= N) return;
    int n = N - 1 - i;                 // descending: high-t first
    int t = 7 * N + n;
    int m = pair[t];
    if (m >= 0) {
        claimed[m] = 1;
        if (argmax[m] < t) atomicMax(&argmax[m], t);
    }
}

__device__ __forceinline__ unsigned cvt_pk_bf16(float lo, float hi) {
    unsigned r;
    asm("v_cvt_pk_bf16_f32 %0, %1, %2" : "=v"(r) : "v"(lo), "v"(hi));
    return r;
}

__device__ __forceinline__ short8 pack8(float4 a, float4 b) {
    union { unsigned u[4]; short8 s; } p;
    p.u[0] = cvt_pk_bf16(a.x, a.y);
    p.u[1] = cvt_pk_bf16(a.z, a.w);
    p.u[2] = cvt_pk_bf16(b.x, b.y);
    p.u[3] = cvt_pk_bf16(b.z, b.w);
    return p.s;
}

// One dispatch, two roles. srest blocks FIRST (short, churn fast), computeA
// blocks behind them -- co-residency overlaps the two phases.
// Correct concurrently: srest touches only unclaimed rows; computeA stores
// only claimed rows (final after s7); its stale unclaimed reads are masked.
__global__ __launch_bounds__(256, 3) void k_mix(
        const float* __restrict__ x, const float* __restrict__ w,
        const int* __restrict__ pair, int* __restrict__ argmax,
        const unsigned char* __restrict__ claimed, float* __restrict__ out,
        int M, int N, int nS) {
    if ((int)blockIdx.x < nS) {
        // ---- scatter_rest role: j=6..0, bytemap+argmax filtered
        int n = blockIdx.x * 256 + threadIdx.x;
        if (n >= N) return;
        for (int j = 6; j >= 0; --j) {
            int t = j * N + n;
            int m = pair[t];
            if (m >= 0 && !claimed[m] && argmax[m] < t)
                atomicMax(&argmax[m], t);
        }
        return;
    }
    // ---- computeA role: R18 compute, j=7-claimed rows only
    const int lane = threadIdx.x & 63;
    const int r16  = lane & 15;
    const int kc   = lane >> 4;
    const int wv   = threadIdx.x >> 6;

    int base = ((blockIdx.x - nS) * 4 + wv) * 64;
    if (base >= M) return;                 // M % 64 == 0

    const int TH = 7 * N;
    int t_[4], n_[4];
    bool cl[4];
#pragma unroll
    for (int st = 0; st < 4; ++st)
        t_[st] = argmax[base + st * 16 + r16];
#pragma unroll
    for (int st = 0; st < 4; ++st) {
        cl[st] = (t_[st] >= TH);           // claimed: final, j=7
        n_[st] = cl[st] ? t_[st] - TH : 0; // unclaimed -> dummy row 0
    }

    short8 bf7[2][2];
#pragma unroll
    for (int ot = 0; ot < 2; ++ot)
#pragma unroll
        for (int kk = 0; kk < 2; ++kk) {
            const float* wp = w + ((ot * 16 + r16) * BLOCK + 7) * IN_CH + kk * 32 + kc * 8;
            bf7[ot][kk] = pack8(*(const float4*)wp, *(const float4*)(wp + 4));
        }

    float4 xs[2][4];
    {
        const float* xp = x + (size_t)n_[0] * IN_CH + kc * 8;
        xs[0][0] = *(const float4*)xp;        xs[0][1] = *(const float4*)(xp + 4);
        xs[0][2] = *(const float4*)(xp + 32); xs[0][3] = *(const float4*)(xp + 36);
    }

#pragma unroll
    for (int st = 0; st < 4; ++st) {
        const int cur = st & 1;
        if (st < 3) {
            const float* xp = x + (size_t)n_[st + 1] * IN_CH + kc * 8;
            xs[cur ^ 1][0] = *(const float4*)xp;        xs[cur ^ 1][1] = *(const float4*)(xp + 4);
            xs[cur ^ 1][2] = *(const float4*)(xp + 32); xs[cur ^ 1][3] = *(const float4*)(xp + 36);
        }
        short8 a0 = pack8(xs[cur][0], xs[cur][1]);
        short8 a1 = pack8(xs[cur][2], xs[cur][3]);

        f32x4v acc0 = {0.f, 0.f, 0.f, 0.f};
        f32x4v acc1 = {0.f, 0.f, 0.f, 0.f};
        acc0 = __builtin_amdgcn_mfma_f32_16x16x32_bf16(a0, bf7[0][0], acc0, 0, 0, 0);
        acc0 = __builtin_amdgcn_mfma_f32_16x16x32_bf16(a1, bf7[0][1], acc0, 0, 0, 0);
        acc1 = __builtin_amdgcn_mfma_f32_16x16x32_bf16(a0, bf7[1][0], acc1, 0, 0, 0);
        acc1 = __builtin_amdgcn_mfma_f32_16x16x32_bf16(a1, bf7[1][1], acc1, 0, 0, 0);

        unsigned long long cb = __ballot(cl[st]);    // row r claimed = bit r
#pragma unroll
        for (int q = 0; q < 4; ++q) {
            int r = kc * 4 + q;
            if ((cb >> r) & 1ull) {
                size_t ro = (size_t)(base + st * 16 + r) * OUT_CH;
                out[ro + r16]      = acc0[q];
                out[ro + 16 + r16] = acc1[q];
            }
        }
    }
}

// finish unclaimed rows (t < 7N, incl. unmapped -> zeros): m-ordered rescan
// of argmax (coalesced, L2-hot); fully-claimed subtiles skipped by ballot.
__global__ __launch_bounds__(256, 3) void k_computeB(
        const float* __restrict__ x, const float* __restrict__ w,
        const int* __restrict__ argmax, float* __restrict__ out, int M, int N) {
    const int lane = threadIdx.x & 63;
    const int r16  = lane & 15;
    const int kc   = lane >> 4;
    const int wv   = threadIdx.x >> 6;

    int base = (blockIdx.x * 4 + wv) * 64;
    if (base >= M) return;

    const int TH = 7 * N;
    const int N1 = N, N2 = 2 * N, N4 = 4 * N;
    int t_[4];
#pragma unroll
    for (int st = 0; st < 4; ++st)
        t_[st] = argmax[base + st * 16 + r16];

#pragma unroll
    for (int st = 0; st < 4; ++st) {
        bool cl = (t_[st] >= TH);
        unsigned long long ub = __ballot(!cl);
        if (ub == 0ull) continue;              // subtile fully claimed

        int v = t_[st], j = 0;
        if (v >= N4) { j = 4;  v -= N4; }
        if (v >= N2) { j += 2; v -= N2; }
        if (v >= N1) { j += 1; v -= N1; }
        int jr = cl ? 9 : ((t_[st] >= 0) ? j : 8);   // 9: never matches
        int n  = (cl || t_[st] < 0) ? 0 : v;

        const float* xp = x + (size_t)n * IN_CH + kc * 8;
        float4 x0 = *(const float4*)xp;
        float4 x1 = *(const float4*)(xp + 4);
        float4 x2 = *(const float4*)(xp + 32);
        float4 x3 = *(const float4*)(xp + 36);
        short8 a0 = pack8(x0, x1);
        short8 a1 = pack8(x2, x3);
        const short8 zz = (short8)0;

        f32x4v acc0 = {0.f, 0.f, 0.f, 0.f};
        f32x4v acc1 = {0.f, 0.f, 0.f, 0.f};
#pragma unroll
        for (int j2 = 0; j2 < 7; ++j2) {       // unclaimed mapped rows: j<=6
            bool pj = (jr == j2);
            if (__ballot(pj) == 0ull) continue;
            short8 m0 = pj ? a0 : zz;
            short8 m1 = pj ? a1 : zz;
            const float* wp0 = w + ((r16)      * BLOCK + j2) * IN_CH + kc * 8;
            const float* wp1 = w + ((16 + r16) * BLOCK + j2) * IN_CH + kc * 8;
            short8 b00 = pack8(*(const float4*)wp0,        *(const float4*)(wp0 + 4));
            short8 b01 = pack8(*(const float4*)(wp0 + 32), *(const float4*)(wp0 + 36));
            short8 b10 = pack8(*(const float4*)wp1,        *(const float4*)(wp1 + 4));
            short8 b11 = pack8(*(const float4*)(wp1 + 32), *(const float4*)(wp1 + 36));
            acc0 = __builtin_amdgcn_mfma_f32_16x16x32_bf16(m0, b00, acc0, 0, 0, 0);
            acc0 = __builtin_amdgcn_mfma_f32_16x16x32_bf16(m1, b01, acc0, 0, 0, 0);
            acc1 = __builtin_amdgcn_mfma_f32_16x16x32_bf16(m0, b10, acc1, 0, 0, 0);
            acc1 = __builtin_amdgcn_mfma_f32_16x16x32_bf16(m1, b11, acc1, 0, 0, 0);
        }

        unsigned long long cb = __ballot(cl);
#pragma unroll
        for (int q = 0; q < 4; ++q) {
            int r = kc * 4 + q;
            if (!((cb >> r) & 1ull)) {         // store only unclaimed rows
                size_t ro = (size_t)(base + st * 16 + r) * OUT_CH;
                out[ro + r16]      = acc0[q];
                out[ro + 16 + r16] = acc1[q];
            }
        }
    }
}

extern "C" void kernel_launch(void* const* d_in, const int* in_sizes, int n_in,
                              void* d_out, int out_size, void* d_ws, size_t ws_size,
                              hipStream_t stream) {
    const float* x    = (const float*)d_in[0];
    const float* w    = (const float*)d_in[1];
    const int*   pair = (const int*)d_in[2];
    int N = in_sizes[0] / IN_CH;     // 400000
    int M = out_size / OUT_CH;       // 200000

    int*           argmax  = (int*)d_ws;
    unsigned char* claimed = (unsigned char*)d_ws + (size_t)M * 4;

    int n4  = M / 4;
    int nc4 = M / 16;
    k_prep<<<(n4 + 255) / 256, 256, 0, stream>>>((int4*)argmax, n4, (int4*)claimed, nc4);

    int gN = (N + 255) / 256;        // 1563 srest blocks
    k_scatter7<<<gN, 256, 0, stream>>>(pair, argmax, claimed, N);

    int nA = (M / 64 + 3) / 4;       // 782 computeA blocks
    k_mix<<<gN + nA, 256, 0, stream>>>(x, w, pair, argmax, claimed,
                                       (float*)d_out, M, N, gN);

    k_computeB<<<nA, 256, 0, stream>>>(x, w, argmax, (float*)d_out, M, N);
}

// Round 24
// 88.320 us; speedup vs baseline: 2.4249x; 1.0622x over previous
//
#include <hip/hip_runtime.h>

#define IN_CH  64
#define OUT_CH 32
#define BLOCK  8

using short8 = __attribute__((ext_vector_type(8))) short;
using f32x4v = __attribute__((ext_vector_type(4))) float;

// ws layout: argmax M*4 | claimed M bytes (L2-resident bytemap).
// FINAL = R18 (best: 88.2us). Pipeline: prep -> scatter7 (+claim bytemap) ->
// scatter_rest (bytemap+argmax filtered) -> m-ordered masked-MFMA compute.
// Probed-and-rejected: bucketing (R10/R13), deeper ILP (R12/R17), occupancy
// 4/SIMD (R21 neutral: BW-bound), coop fusion (R14 fails capture), role-mix
// overlap (R22 regalloc collapse / R23 net -5.6).

__global__ void k_prep(int4* __restrict__ argmax4, int n4, int4* __restrict__ claimed4, int nc4) {
    int i = blockIdx.x * 256 + threadIdx.x;
    if (i < n4) argmax4[i] = make_int4(-1, -1, -1, -1);
    if (i < nc4) claimed4[i] = make_int4(0, 0, 0, 0);
}

// argmax[m] monotone non-decreasing => stale read is a valid lower bound;
// filtered atomicMax is always correct. claimed[m]=1 for EVERY valid j=7
// mapping; rest pass skips claimed rows (their winner t>=7N is committed
// at the dispatch boundary).
__global__ void k_scatter7(const int* __restrict__ pair, int* __restrict__ argmax,
                           unsigned char* __restrict__ claimed, int N) {
    int i = blockIdx.x * 256 + threadIdx.x;
    if (i >= N) return;
    int n = N - 1 - i;                 // descending: high-t first
    int t = 7 * N + n;
    int m = pair[t];
    if (m >= 0) {
        claimed[m] = 1;
        if (argmax[m] < t) atomicMax(&argmax[m], t);
    }
}

__global__ void k_scatter_rest(const int* __restrict__ pair, int* __restrict__ argmax,
                               const unsigned char* __restrict__ claimed, int N) {
    int n = blockIdx.x * 256 + threadIdx.x;
    if (n >= N) return;
    for (int j = 6; j >= 0; --j) {
        int t = j * N + n;
        int m = pair[t];
        if (m >= 0 && !claimed[m] && argmax[m] < t)
            atomicMax(&argmax[m], t);
    }
}

__device__ __forceinline__ unsigned cvt_pk_bf16(float lo, float hi) {
    unsigned r;
    asm("v_cvt_pk_bf16_f32 %0, %1, %2" : "=v"(r) : "v"(lo), "v"(hi));
    return r;
}

__device__ __forceinline__ short8 pack8(float4 a, float4 b) {
    union { unsigned u[4]; short8 s; } p;
    p.u[0] = cvt_pk_bf16(a.x, a.y);
    p.u[1] = cvt_pk_bf16(a.z, a.w);
    p.u[2] = cvt_pk_bf16(b.x, b.y);
    p.u[3] = cvt_pk_bf16(b.z, b.w);
    return p.s;
}

// m-ordered masked MFMA, fill-free: wave owns 64 consecutive out rows
// (4x16 subtiles), reads argmax directly, decodes j,n branch-free, runs
// MFMA only for j's present (ballot-skip). j=7 B resident in 16 VGPRs;
// other j's demand-loaded from L2-hot w. Dense coalesced stores.
__global__ __launch_bounds__(256, 3) void k_compute(
        const float* __restrict__ x, const float* __restrict__ w,
        const int* __restrict__ argmax, float* __restrict__ out,
        int M, int N) {
    const int lane = threadIdx.x & 63;
    const int r16  = lane & 15;
    const int kc   = lane >> 4;
    const int wv   = threadIdx.x >> 6;

    int base = (blockIdx.x * 4 + wv) * 64;
    if (base >= M) return;                 // M % 64 == 0: no row tails

    int t_[4];
#pragma unroll
    for (int st = 0; st < 4; ++st)
        t_[st] = argmax[base + st * 16 + r16];
    const int N1 = N, N2 = 2 * N, N4 = 4 * N;
    int j_[4], n_[4];
#pragma unroll
    for (int st = 0; st < 4; ++st) {
        int v = t_[st], j = 0;
        if (v >= N4) { j = 4;  v -= N4; }
        if (v >= N2) { j += 2; v -= N2; }
        if (v >= N1) { j += 1; v -= N1; }
        bool ok = t_[st] >= 0;
        j_[st] = ok ? j : 8;               // 8 = unmapped sentinel
        n_[st] = ok ? v : 0;
    }

    short8 bf7[2][2];
#pragma unroll
    for (int ot = 0; ot < 2; ++ot)
#pragma unroll
        for (int kk = 0; kk < 2; ++kk) {
            const float* wp = w + ((ot * 16 + r16) * BLOCK + 7) * IN_CH + kk * 32 + kc * 8;
            bf7[ot][kk] = pack8(*(const float4*)wp, *(const float4*)(wp + 4));
        }

    float4 xs[2][4];
    {
        const float* xp = x + (size_t)n_[0] * IN_CH + kc * 8;
        xs[0][0] = *(const float4*)xp;        xs[0][1] = *(const float4*)(xp + 4);
        xs[0][2] = *(const float4*)(xp + 32); xs[0][3] = *(const float4*)(xp + 36);
    }

#pragma unroll
    for (int st = 0; st < 4; ++st) {
        const int cur = st & 1;
        if (st < 3) {
            const float* xp = x + (size_t)n_[st + 1] * IN_CH + kc * 8;
            xs[cur ^ 1][0] = *(const float4*)xp;        xs[cur ^ 1][1] = *(const float4*)(xp + 4);
            xs[cur ^ 1][2] = *(const float4*)(xp + 32); xs[cur ^ 1][3] = *(const float4*)(xp + 36);
        }

        short8 a0 = pack8(xs[cur][0], xs[cur][1]);   // k 0..31
        short8 a1 = pack8(xs[cur][2], xs[cur][3]);   // k 32..63
        const int jr = j_[st];
        const short8 zz = (short8)0;

        f32x4v acc0 = {0.f, 0.f, 0.f, 0.f};
        f32x4v acc1 = {0.f, 0.f, 0.f, 0.f};
#pragma unroll
        for (int j = 0; j < 8; ++j) {
            bool pj = (jr == j);
            if (__ballot(pj) == 0ull) continue;      // skip absent j's
            short8 m0 = pj ? a0 : zz;
            short8 m1 = pj ? a1 : zz;
            short8 b00, b01, b10, b11;
            if (j == 7) {
                b00 = bf7[0][0]; b01 = bf7[0][1];
                b10 = bf7[1][0]; b11 = bf7[1][1];
            } else {
                const float* wp0 = w + ((r16)      * BLOCK + j) * IN_CH + kc * 8;
                const float* wp1 = w + ((16 + r16) * BLOCK + j) * IN_CH + kc * 8;
                b00 = pack8(*(const float4*)wp0,        *(const float4*)(wp0 + 4));
                b01 = pack8(*(const float4*)(wp0 + 32), *(const float4*)(wp0 + 36));
                b10 = pack8(*(const float4*)wp1,        *(const float4*)(wp1 + 4));
                b11 = pack8(*(const float4*)(wp1 + 32), *(const float4*)(wp1 + 36));
            }
            acc0 = __builtin_amdgcn_mfma_f32_16x16x32_bf16(m0, b00, acc0, 0, 0, 0);
            acc0 = __builtin_amdgcn_mfma_f32_16x16x32_bf16(m1, b01, acc0, 0, 0, 0);
            acc1 = __builtin_amdgcn_mfma_f32_16x16x32_bf16(m0, b10, acc1, 0, 0, 0);
            acc1 = __builtin_amdgcn_mfma_f32_16x16x32_bf16(m1, b11, acc1, 0, 0, 0);
        }

#pragma unroll
        for (int q = 0; q < 4; ++q) {
            size_t ro = (size_t)(base + st * 16 + kc * 4 + q) * OUT_CH;
            out[ro + r16]      = acc0[q];
            out[ro + 16 + r16] = acc1[q];
        }
    }
}

extern "C" void kernel_launch(void* const* d_in, const int* in_sizes, int n_in,
                              void* d_out, int out_size, void* d_ws, size_t ws_size,
                              hipStream_t stream) {
    const float* x    = (const float*)d_in[0];
    const float* w    = (const float*)d_in[1];
    const int*   pair = (const int*)d_in[2];
    int N = in_sizes[0] / IN_CH;     // 400000
    int M = out_size / OUT_CH;       // 200000

    int*           argmax  = (int*)d_ws;
    unsigned char* claimed = (unsigned char*)d_ws + (size_t)M * 4;

    int n4  = M / 4;                 // M % 4 == 0
    int nc4 = M / 16;                // claimed bytes as int4
    k_prep<<<(n4 + 255) / 256, 256, 0, stream>>>((int4*)argmax, n4, (int4*)claimed, nc4);

    int gN = (N + 255) / 256;
    k_scatter7    <<<gN, 256, 0, stream>>>(pair, argmax, claimed, N);  // j=7, high-t first
    k_scatter_rest<<<gN, 256, 0, stream>>>(pair, argmax, claimed, N);  // j=6..0, bytemap-filtered

    int tiles  = M / 64;             // 3125
    int blocks = (tiles + 3) / 4;    // 782
    k_compute<<<blocks, 256, 0, stream>>>(x, w, argmax, (float*)d_out, M, N);
}